// Round 11
// baseline (74.108 us; speedup 1.0000x reference)
//
#include <hip/hip_runtime.h>

// Problem constants (fixed by setup_inputs)
#define B_    16
#define N_    262144            // 2^18 pixels per image
#define NC    150               // classes
#define NP    4096              // pred segment ids
#define T_    (B_ * NC)         // 2400 distinct target ids
#define TOTAL (B_ * N_)         // 4,194,304 pixels

// partition: 256 parent buckets (pred>>4)
#define PBKT       256
#define PCAP       18432        // mean 16384, +16 sigma
#define KEY_SHIFT  16           // local key = (p&15)*2400 + t < 38400 < 2^16
#define P1_BLOCKS  2048
#define P1_PIX     (TOTAL / P1_BLOCKS)   // 2048 pixels per block (one image)
#define P1_PER_THR (P1_PIX / 256)        // 8 per thread

// iou: 8 co-blocks per parent bucket, each owns 2 pred rows
#define SUBQ       8
#define QP         2            // pred rows per co-block
#define QT         (QP * T_)    // 4800 local keys per co-block

// gCount padded: one counter per 256 B (own L2 line) -> no atomic serialization
#define CSTRIDE    64
#define NCOUNTERS  (PBKT * CSTRIDE + T_)   // 16384 + 2400 = 18784 u32

typedef unsigned int u32;
typedef unsigned short u16;

// ---------------------------------------------------------------------------
// Kernel 0: zero the counters (padded gCount + gNT)
// ---------------------------------------------------------------------------
__global__ __launch_bounds__(256) void init_kernel(u32* __restrict__ ctrs) {
    int i = blockIdx.x * 256 + threadIdx.x;
    if (i < NCOUNTERS) ctrs[i] = 0;
}

// ---------------------------------------------------------------------------
// Kernel 1: radix-split pixels into 256 parent buckets (+ fused n_tgt).
// Wave-private histograms (cnt4/nth4) kill cross-wave LDS-atomic contention;
// 17 KB LDS + VGPR<=64 -> 8 blocks/CU (32 waves) to hide atomic latency.
// ---------------------------------------------------------------------------
__global__ __launch_bounds__(256, 8) void partition_kernel(const int* __restrict__ pred,
                                                           const int* __restrict__ tgt,
                                                           u16* __restrict__ records,
                                                           u32* __restrict__ gCount,
                                                           u32* __restrict__ gNT) {
    __shared__ u32 cnt4[4][PBKT];    // per-wave counts, then per-wave cursors (4 KB)
    __shared__ u32 lstart[PBKT];     // 1 KB
    __shared__ u32 goff[PBKT];       // 1 KB (gbase - lstart)
    __shared__ u32 nth4[4][160];     // per-wave class hist (2.5 KB, 150 used)
    __shared__ u32 wsum[4];
    __shared__ u32 staging[P1_PIX];  // 8 KB

    int tid = threadIdx.x;
    int w   = tid >> 6;
    #pragma unroll
    for (int i = 0; i < 4; ++i) cnt4[i][tid] = 0;
    if (tid < 160) {
        #pragma unroll
        for (int i = 0; i < 4; ++i) nth4[i][tid] = 0;
    }

    int base = blockIdx.x * P1_PIX;
    int b_img = base >> 18;                  // constant per block (128 blocks/image)
    const int4* pred4 = (const int4*)pred;
    const int4* tgt4  = (const int4*)tgt;
    int4 pv[2], tv[2];
    #pragma unroll
    for (int k = 0; k < 2; ++k) {
        int vi = (base >> 2) + k * 256 + tid;
        pv[k] = pred4[vi];
        tv[k] = tgt4[vi];
    }
    __syncthreads();

    u32 keys[P1_PER_THR];
    #pragma unroll
    for (int k = 0; k < 2; ++k) {
        int pe[4] = {pv[k].x, pv[k].y, pv[k].z, pv[k].w};
        int te[4] = {tv[k].x, tv[k].y, tv[k].z, tv[k].w};
        #pragma unroll
        for (int e = 0; e < 4; ++e) {
            int p = pe[e];
            u32 bkt = (u32)(p >> 4);
            u32 lk  = (u32)((p & 15) * T_ + b_img * NC + te[e]);
            keys[k * 4 + e] = (bkt << KEY_SHIFT) | lk;
            atomicAdd(&cnt4[w][bkt], 1u);
            atomicAdd(&nth4[w][te[e]], 1u);
        }
    }
    __syncthreads();

    // per-bucket totals + exclusive scan (wave shfl) + per-wave cursors
    {
        u32 c0 = cnt4[0][tid], c1 = cnt4[1][tid], c2 = cnt4[2][tid], c3 = cnt4[3][tid];
        u32 myc = c0 + c1 + c2 + c3;
        u32 v = myc;
        #pragma unroll
        for (int o = 1; o < 64; o <<= 1) {
            u32 t = __shfl_up(v, o);
            if ((tid & 63) >= o) v += t;
        }
        if ((tid & 63) == 63) wsum[w] = v;
        __syncthreads();
        u32 woff = 0;
        #pragma unroll
        for (int ww = 0; ww < 3; ++ww) woff += (ww < w) ? wsum[ww] : 0;
        u32 ex = v + woff - myc;                 // exclusive prefix over buckets
        lstart[tid] = ex;
        // per-wave scatter cursors (reuse cnt4 storage)
        cnt4[0][tid] = ex;
        cnt4[1][tid] = ex + c0;
        cnt4[2][tid] = ex + c0 + c1;
        cnt4[3][tid] = ex + c0 + c1 + c2;
        u32 gb = atomicAdd(&gCount[tid * CSTRIDE], myc);
        goff[tid] = gb - ex;
    }
    if (tid < NC) {
        u32 s = nth4[0][tid] + nth4[1][tid] + nth4[2][tid] + nth4[3][tid];
        if (s) atomicAdd(&gNT[b_img * NC + tid], s);
    }
    __syncthreads();

    // scatter into LDS staging (contention only within own wave)
    #pragma unroll
    for (int k = 0; k < P1_PER_THR; ++k) {
        u32 v = keys[k];
        u32 pos = atomicAdd(&cnt4[w][v >> KEY_SHIFT], 1u);
        staging[pos] = v;
    }
    __syncthreads();

    // coalesced flush: ~8-record (16 B) runs per bucket
    for (int r = tid; r < P1_PIX; r += 256) {
        u32 v = staging[r];
        u32 bkt = v >> KEY_SHIFT;
        u32 gp = goff[bkt] + (u32)r;             // = gbase + (r - lstart)
        if (gp < PCAP) records[(size_t)bkt * PCAP + gp] = (u16)(v & 0xFFFFu);
    }
}

// ---------------------------------------------------------------------------
// Kernel 2: 8 co-blocks per parent bucket, each owning 2 pred rows.
// blockIdx = q*256 + bkt -> all co-blocks of bucket b on XCD (b&7): records
// slice L3-filled once, L2-hit for the other seven. LDS 12.9 KB -> 8 blk/CU.
// ---------------------------------------------------------------------------
__global__ __launch_bounds__(256, 8) void iou_kernel(const u16* __restrict__ records,
                                                     const u32* __restrict__ gCount,
                                                     const u32* __restrict__ gNT,
                                                     const float* __restrict__ targets,
                                                     float* __restrict__ out) {
    __shared__ u32 hist[QT / 2];              // 2400 words = 9.6 KB
    __shared__ float npred_part[4];
    __shared__ float iou_pc[QP][NC];          // 1.2 KB
    __shared__ float2 red2[256];              // 2 KB

    int tid = threadIdx.x;
    int bkt = blockIdx.x & 255;               // XCD co-location
    int q   = blockIdx.x >> 8;                // 0..7
    u32 lo = (u32)(q * QT);

    // vectorized hist zero
    {
        uint4 z4 = make_uint4(0u, 0u, 0u, 0u);
        uint4* h4 = (uint4*)hist;
        for (int j = tid; j < QT / 8; j += 256) h4[j] = z4;
    }
    __syncthreads();

    u32 cnt = gCount[bkt * CSTRIDE];
    if (cnt > PCAP) cnt = PCAP;
    const u16* rec = records + (size_t)bkt * PCAP;

    // vectorized scan (8 B/lane), 1-deep prefetch, single-compare filter
    u32 nv4 = cnt >> 2;
    const ushort4* rec4 = (const ushort4*)rec;
    {
        u32 r = tid;
        ushort4 cur;
        if (r < nv4) cur = rec4[r];
        for (; r < nv4; ) {
            u32 rn = r + 256;
            ushort4 nxt;
            if (rn < nv4) nxt = rec4[rn];
            u32 e[4] = {cur.x, cur.y, cur.z, cur.w};
            #pragma unroll
            for (int i = 0; i < 4; ++i) {
                u32 lk = e[i] - lo;
                if (lk < (u32)QT)
                    atomicAdd(&hist[lk >> 1], (lk & 1u) ? 65536u : 1u);
            }
            cur = nxt;
            r = rn;
        }
    }
    for (u32 r = (nv4 << 2) + tid; r < cnt; r += 256) {
        u32 lk = (u32)rec[r] - lo;
        if (lk < (u32)QT)
            atomicAdd(&hist[lk >> 1], (lk & 1u) ? 65536u : 1u);
    }
    __syncthreads();

    // n_pred row sums: 128 threads per pred row (1200 words each)
    {
        int pl = tid >> 7, lane128 = tid & 127;
        u32 s = 0;
        for (int wd = lane128; wd < T_ / 2; wd += 128) {
            u32 v = hist[pl * (T_ / 2) + wd];
            s += (v & 0xFFFFu) + (v >> 16);
        }
        #pragma unroll
        for (int o = 32; o > 0; o >>= 1) s += __shfl_xor(s, o);
        if ((tid & 63) == 0) npred_part[tid >> 6] = (float)s;
    }
    __syncthreads();

    // iou_pc[pl][c] = sum_b O/(n_pred + n_tgt - O); gNT reads are L1-hot
    for (int idx = tid; idx < QP * NC; idx += 256) {
        int pl = idx / NC, cls = idx - pl * NC;
        float np = npred_part[2 * pl] + npred_part[2 * pl + 1];
        float acc = 0.f;
        #pragma unroll
        for (int b = 0; b < B_; ++b) {
            int lk = pl * T_ + b * NC + cls;
            u32 w = hist[lk >> 1];
            u32 v = (lk & 1) ? (w >> 16) : (w & 0xFFFFu);
            if (v) {
                float fv = (float)v;
                acc += fv * __builtin_amdgcn_rcpf(np + (float)gNT[b * NC + cls] - fv);
            }
        }
        iou_pc[pl][cls] = acc;
    }
    __syncthreads();

    // matmul with targets (each element read once for both rows)
    float o0 = 0.f, o1 = 0.f;
    if (tid < NC) {
        for (int k = 0; k < NC; ++k) {
            float tv = targets[k * NC + tid];
            o0 += iou_pc[0][k] * tv;
            o1 += iou_pc[1][k] * tv;
        }
    }

    // single float2 tree reduction for the 2 denominators
    red2[tid] = (tid < NC) ? make_float2(o0, o1) : make_float2(0.f, 0.f);
    __syncthreads();
    for (int o = 128; o > 0; o >>= 1) {
        if (tid < o) {
            float2 a = red2[tid], b = red2[tid + o];
            red2[tid] = make_float2(a.x + b.x, a.y + b.y);
        }
        __syncthreads();
    }
    float2 den = red2[0];

    if (tid < NC) {
        size_t ob = (size_t)(bkt * 16 + q * QP) * NC + tid;
        out[ob + 0 * NC] = o0 * __builtin_amdgcn_rcpf(den.x);
        out[ob + 1 * NC] = o1 * __builtin_amdgcn_rcpf(den.y);
    }
}

// ---------------------------------------------------------------------------
extern "C" void kernel_launch(void* const* d_in, const int* in_sizes, int n_in,
                              void* d_out, int out_size, void* d_ws, size_t ws_size,
                              hipStream_t stream) {
    const int*   pred    = (const int*)d_in[0];
    const int*   tgt     = (const int*)d_in[1];
    const float* targets = (const float*)d_in[2];
    float*       out     = (float*)d_out;

    u32* gCount  = (u32*)d_ws;                          // 256 * CSTRIDE (64 KB)
    u32* gNT     = gCount + PBKT * CSTRIDE;             // 2400
    u16* records = (u16*)(gNT + T_);                    // 256*18432 u16 = 9.4 MB

    init_kernel<<<(NCOUNTERS + 255) / 256, 256, 0, stream>>>((u32*)d_ws);
    partition_kernel<<<P1_BLOCKS, 256, 0, stream>>>(pred, tgt, records, gCount, gNT);
    iou_kernel<<<PBKT * SUBQ, 256, 0, stream>>>(records, gCount, gNT, targets, out);
}

// Round 12
// 62.391 us; speedup vs baseline: 1.1878x; 1.1878x over previous
//
#include <hip/hip_runtime.h>

// Problem constants (fixed by setup_inputs)
#define B_    16
#define N_    262144            // 2^18 pixels per image
#define NC    150               // classes
#define NP    4096              // pred segment ids
#define T_    (B_ * NC)         // 2400 distinct target ids
#define TOTAL (B_ * N_)         // 4,194,304 pixels

// partition: 256 parent buckets (pred>>4)
#define PBKT       256
#define PCAP       18432        // mean 16384, +16 sigma
#define KEY_SHIFT  16           // local key = (p&15)*2400 + t < 38400 < 2^16
#define P1_BLOCKS  1024
#define P1_PIX     (TOTAL / P1_BLOCKS)   // 4096 pixels per block (one image)

// iou: 4 co-blocks per parent bucket, each owns 4 pred rows
#define QT         9600         // local keys per quadrant (4*2400)

// gCount padded: one counter per 256 B (own L2 line) -> no atomic serialization
#define CSTRIDE    64
#define NCOUNTERS  (PBKT * CSTRIDE + T_)   // 16384 + 2400 = 18784 u32

typedef unsigned int u32;
typedef unsigned short u16;

// ---------------------------------------------------------------------------
// Kernel 0: zero the counters (padded gCount + gNT)
// ---------------------------------------------------------------------------
__global__ __launch_bounds__(256) void init_kernel(u32* __restrict__ ctrs) {
    int i = blockIdx.x * 256 + threadIdx.x;
    if (i < NCOUNTERS) ctrs[i] = 0;
}

// ---------------------------------------------------------------------------
// Kernel 1: radix-split pixels into 256 parent buckets (+ fused n_tgt).
// Two-pass recompute: phase A counts, phase C re-reads inputs (L2-hot) and
// recomputes keys for the scatter. No keys[] in registers -> VGPR < 64 ->
// with 18.7 KB LDS: 8 blocks/CU (32 waves) to hide LDS-atomic latency.
// ---------------------------------------------------------------------------
__global__ __launch_bounds__(256, 8) void partition_kernel(const int* __restrict__ pred,
                                                           const int* __restrict__ tgt,
                                                           u16* __restrict__ records,
                                                           u32* __restrict__ gCount,
                                                           u32* __restrict__ gNT) {
    __shared__ u32 cursor[PBKT];     // counts in phase A, cursors in phase C (1 KB)
    __shared__ u32 goff[PBKT];       // gbase - lstart (1 KB)
    __shared__ u32 nth[NC];          // class histogram (600 B)
    __shared__ u32 wsum[4];
    __shared__ u32 staging[P1_PIX];  // 16 KB

    int tid = threadIdx.x;
    cursor[tid] = 0;
    if (tid < NC) nth[tid] = 0;
    __syncthreads();

    int base = blockIdx.x * P1_PIX;
    int b_img = base >> 18;                  // constant per block
    const int4* pred4 = (const int4*)pred;
    const int4* tgt4  = (const int4*)tgt;

    // ---- phase A: count buckets + classes (no key storage) ----
    #pragma unroll
    for (int k = 0; k < 4; ++k) {
        int vi = (base >> 2) + k * 256 + tid;
        int4 pv = pred4[vi];
        int4 tv = tgt4[vi];
        atomicAdd(&cursor[(u32)pv.x >> 4], 1u);
        atomicAdd(&cursor[(u32)pv.y >> 4], 1u);
        atomicAdd(&cursor[(u32)pv.z >> 4], 1u);
        atomicAdd(&cursor[(u32)pv.w >> 4], 1u);
        atomicAdd(&nth[tv.x], 1u);
        atomicAdd(&nth[tv.y], 1u);
        atomicAdd(&nth[tv.z], 1u);
        atomicAdd(&nth[tv.w], 1u);
    }
    __syncthreads();

    // ---- phase B: exclusive scan (wave shfl) + global base assignment ----
    {
        u32 myc = cursor[tid];
        u32 v = myc;
        #pragma unroll
        for (int o = 1; o < 64; o <<= 1) {
            u32 t = __shfl_up(v, o);
            if ((tid & 63) >= o) v += t;
        }
        if ((tid & 63) == 63) wsum[tid >> 6] = v;
        __syncthreads();
        u32 woff = 0;
        #pragma unroll
        for (int w = 0; w < 3; ++w) woff += (w < (tid >> 6)) ? wsum[w] : 0;
        u32 ex = v + woff - myc;                 // exclusive prefix
        cursor[tid] = ex;                        // becomes scatter cursor
        u32 gb = atomicAdd(&gCount[tid * CSTRIDE], myc);
        goff[tid] = gb - ex;
    }
    if (tid < NC && nth[tid]) atomicAdd(&gNT[b_img * NC + tid], nth[tid]);
    __syncthreads();

    // ---- phase C: re-read inputs (L2/L3-hot), recompute keys, scatter ----
    #pragma unroll
    for (int k = 0; k < 4; ++k) {
        int vi = (base >> 2) + k * 256 + tid;
        int4 pv = pred4[vi];
        int4 tv = tgt4[vi];
        int pe[4] = {pv.x, pv.y, pv.z, pv.w};
        int te[4] = {tv.x, tv.y, tv.z, tv.w};
        #pragma unroll
        for (int e = 0; e < 4; ++e) {
            int p = pe[e];
            u32 bkt = (u32)(p >> 4);
            u32 lk  = (u32)((p & 15) * T_ + b_img * NC + te[e]);
            u32 pos = atomicAdd(&cursor[bkt], 1u);
            staging[pos] = (bkt << KEY_SHIFT) | lk;
        }
    }
    __syncthreads();

    // ---- phase D: coalesced flush: ~16-record (32 B) runs per bucket ----
    for (int r = tid; r < P1_PIX; r += 256) {
        u32 v = staging[r];
        u32 bkt = v >> KEY_SHIFT;
        u32 gp = goff[bkt] + (u32)r;             // = gbase + (r - lstart)
        if (gp < PCAP) records[(size_t)bkt * PCAP + gp] = (u16)(v & 0xFFFFu);
    }
}

// ---------------------------------------------------------------------------
// Kernel 2: 4 co-blocks per parent bucket, each owning 4 pred rows.
// bkt = blockIdx&255 -> co-blocks {b,256+b,512+b,768+b} on the same XCD.
// LDS 21.7 KB -> 7 blocks/CU.
// ---------------------------------------------------------------------------
__global__ __launch_bounds__(256, 7) void iou_kernel(const u16* __restrict__ records,
                                                     const u32* __restrict__ gCount,
                                                     const u32* __restrict__ gNT,
                                                     const float* __restrict__ targets,
                                                     float* __restrict__ out) {
    __shared__ u32 hist[QT / 2];              // 4800 words = 19.2 KB
    __shared__ float npred_s[4];
    __shared__ float iou_pc[4][NC];           // 2.4 KB
    __shared__ float4 wred[4];                // per-wave partial denominators

    int tid = threadIdx.x;
    int bkt = blockIdx.x & 255;               // XCD co-location swizzle
    int q   = blockIdx.x >> 8;
    u32 lo = (u32)(q * QT);

    // vectorized hist zero
    {
        uint4 z4 = make_uint4(0u, 0u, 0u, 0u);
        uint4* h4 = (uint4*)hist;
        for (int j = tid; j < QT / 8; j += 256) h4[j] = z4;
    }
    __syncthreads();

    u32 cnt = gCount[bkt * CSTRIDE];
    if (cnt > PCAP) cnt = PCAP;
    const u16* rec = records + (size_t)bkt * PCAP;

    // vectorized scan (8 B/lane), 1-deep prefetch, single-compare filter
    u32 nv4 = cnt >> 2;
    const ushort4* rec4 = (const ushort4*)rec;
    {
        u32 r = tid;
        ushort4 cur;
        if (r < nv4) cur = rec4[r];
        for (; r < nv4; ) {
            u32 rn = r + 256;
            ushort4 nxt;
            if (rn < nv4) nxt = rec4[rn];
            u32 e[4] = {cur.x, cur.y, cur.z, cur.w};
            #pragma unroll
            for (int i = 0; i < 4; ++i) {
                u32 lk = e[i] - lo;
                if (lk < (u32)QT)
                    atomicAdd(&hist[lk >> 1], (lk & 1u) ? 65536u : 1u);
            }
            cur = nxt;
            r = rn;
        }
    }
    for (u32 r = (nv4 << 2) + tid; r < cnt; r += 256) {
        u32 lk = (u32)rec[r] - lo;
        if (lk < (u32)QT)
            atomicAdd(&hist[lk >> 1], (lk & 1u) ? 65536u : 1u);
    }
    __syncthreads();

    // n_pred row sums: 4 waves, one pred row each (1200 words)
    {
        int pl = tid >> 6, lane = tid & 63;
        u32 s = 0;
        for (int w = lane; w < T_ / 2; w += 64) {
            u32 v = hist[pl * (T_ / 2) + w];
            s += (v & 0xFFFFu) + (v >> 16);
        }
        #pragma unroll
        for (int o = 32; o > 0; o >>= 1) s += __shfl_xor(s, o);
        if (lane == 0) npred_s[pl] = (float)s;
    }
    __syncthreads();

    // iou_pc[pl][c] = sum_b O/(n_pred + n_tgt - O); gNT reads are L1-hot
    for (int idx = tid; idx < 4 * NC; idx += 256) {
        int pl = idx / NC, cls = idx - pl * NC;
        float np = npred_s[pl];
        float acc = 0.f;
        #pragma unroll
        for (int b = 0; b < B_; ++b) {
            int lk = pl * T_ + b * NC + cls;
            u32 w = hist[lk >> 1];
            u32 v = (lk & 1) ? (w >> 16) : (w & 0xFFFFu);
            if (v) {
                float fv = (float)v;
                acc += fv * __builtin_amdgcn_rcpf(np + (float)gNT[b * NC + cls] - fv);
            }
        }
        iou_pc[pl][cls] = acc;
    }
    __syncthreads();

    // matmul with targets (each element read once for all 4 rows)
    float o0 = 0.f, o1 = 0.f, o2 = 0.f, o3 = 0.f;
    if (tid < NC) {
        for (int k = 0; k < NC; ++k) {
            float tv = targets[k * NC + tid];
            o0 += iou_pc[0][k] * tv;
            o1 += iou_pc[1][k] * tv;
            o2 += iou_pc[2][k] * tv;
            o3 += iou_pc[3][k] * tv;
        }
    }

    // denominator: wave shfl reduce -> 4 partials -> broadcast sum
    {
        float4 v = (tid < NC) ? make_float4(o0, o1, o2, o3)
                              : make_float4(0.f, 0.f, 0.f, 0.f);
        #pragma unroll
        for (int o = 32; o > 0; o >>= 1) {
            v.x += __shfl_xor(v.x, o);
            v.y += __shfl_xor(v.y, o);
            v.z += __shfl_xor(v.z, o);
            v.w += __shfl_xor(v.w, o);
        }
        if ((tid & 63) == 0) wred[tid >> 6] = v;
    }
    __syncthreads();
    float4 den;
    {
        float4 a = wred[0], b = wred[1], c = wred[2], d = wred[3];
        den = make_float4(a.x + b.x + c.x + d.x, a.y + b.y + c.y + d.y,
                          a.z + b.z + c.z + d.z, a.w + b.w + c.w + d.w);
    }

    if (tid < NC) {
        size_t ob = (size_t)(bkt * 16 + q * 4) * NC + tid;
        out[ob + 0 * NC] = o0 * __builtin_amdgcn_rcpf(den.x);
        out[ob + 1 * NC] = o1 * __builtin_amdgcn_rcpf(den.y);
        out[ob + 2 * NC] = o2 * __builtin_amdgcn_rcpf(den.z);
        out[ob + 3 * NC] = o3 * __builtin_amdgcn_rcpf(den.w);
    }
}

// ---------------------------------------------------------------------------
extern "C" void kernel_launch(void* const* d_in, const int* in_sizes, int n_in,
                              void* d_out, int out_size, void* d_ws, size_t ws_size,
                              hipStream_t stream) {
    const int*   pred    = (const int*)d_in[0];
    const int*   tgt     = (const int*)d_in[1];
    const float* targets = (const float*)d_in[2];
    float*       out     = (float*)d_out;

    u32* gCount  = (u32*)d_ws;                          // 256 * CSTRIDE (64 KB)
    u32* gNT     = gCount + PBKT * CSTRIDE;             // 2400
    u16* records = (u16*)(gNT + T_);                    // 256*18432 u16 = 9.4 MB

    init_kernel<<<(NCOUNTERS + 255) / 256, 256, 0, stream>>>((u32*)d_ws);
    partition_kernel<<<P1_BLOCKS, 256, 0, stream>>>(pred, tgt, records, gCount, gNT);
    iou_kernel<<<PBKT * 4, 256, 0, stream>>>(records, gCount, gNT, targets, out);
}